// Round 1
// baseline (406.039 us; speedup 1.0000x reference)
//
#include <hip/hip_runtime.h>
#include <cstdint>

// Problem constants (from reference)
#define N_NODES   50000
#define N_IN      512
#define HIDDEN    64
#define N_CLASSES 40
#define N_EDGES   800000

// Workspace layout (byte offsets, all 16B-aligned)
#define OFF_HA   0u            // 50000*64*4 = 12,800,000
#define OFF_HB   12800000u     // 12,800,000
#define OFF_CNTR 25600000u     // 50000 ints (deg counts over row)
#define OFF_CNTC 25800000u     // 50000 ints (counts over col)
#define OFF_CUR  26000000u     // 50000 ints (fill cursors)
#define OFF_DIS  26200000u     // 50000 floats (deg^-0.5)
#define OFF_OFFS 26400000u     // 50001 ints (CSR offsets)
#define OFF_BSUM 26600704u     // 49 ints (scan block sums)
#define OFF_ESRC 26601216u     // 800000 ints
#define OFF_ENRM 29801216u     // 800000 floats
// total ~33.0 MB

__global__ __launch_bounds__(256) void zero_i32(int* p, int n) {
    int i = blockIdx.x * 256 + threadIdx.x;
    if (i < n) p[i] = 0;
}

__global__ __launch_bounds__(256) void count_k(const int* __restrict__ erow,
                                               const int* __restrict__ ecol,
                                               int* __restrict__ cnt_row,
                                               int* __restrict__ cnt_col) {
    int e = blockIdx.x * 256 + threadIdx.x;
    if (e >= N_EDGES) return;
    atomicAdd(&cnt_row[erow[e]], 1);
    atomicAdd(&cnt_col[ecol[e]], 1);
}

__global__ __launch_bounds__(256) void dis_k(const int* __restrict__ cnt_row,
                                             float* __restrict__ disv) {
    int i = blockIdx.x * 256 + threadIdx.x;
    if (i >= N_NODES) return;
    disv[i] = rsqrtf((float)(cnt_row[i] + 1));   // +1 self loop
}

// ---- exclusive scan of cnt_col (50000) -> offs ----
__global__ __launch_bounds__(256) void scan1(const int* __restrict__ in,
                                             int* __restrict__ out,
                                             int* __restrict__ bsum, int n) {
    int t = threadIdx.x;
    int base = blockIdx.x * 1024;
    int g = base + t * 4;
    int v[4];
#pragma unroll
    for (int i = 0; i < 4; i++) v[i] = (g + i < n) ? in[g + i] : 0;
    int s = v[0] + v[1] + v[2] + v[3];
    int lane = t & 63, wid = t >> 6;
    int x = s;
#pragma unroll
    for (int d = 1; d < 64; d <<= 1) {
        int y = __shfl_up(x, d);
        if (lane >= d) x += y;
    }
    __shared__ int wt[4];
    if (lane == 63) wt[wid] = x;
    __syncthreads();
    int wo = 0;
    for (int w = 0; w < wid; w++) wo += wt[w];
    int run = wo + x - s;   // exclusive prefix of this thread's 4 elems
#pragma unroll
    for (int i = 0; i < 4; i++) {
        if (g + i < n) out[g + i] = run;
        run += v[i];
    }
    if (t == 255) bsum[blockIdx.x] = wo + x;
}

__global__ void scan2(int* bsum, int nb) {
    int lane = threadIdx.x;   // launched with 64 threads
    int v = (lane < nb) ? bsum[lane] : 0;
    int x = v;
#pragma unroll
    for (int d = 1; d < 64; d <<= 1) {
        int y = __shfl_up(x, d);
        if (lane >= d) x += y;
    }
    if (lane < nb) bsum[lane] = x - v;   // exclusive
}

__global__ __launch_bounds__(256) void scan3(int* __restrict__ offs,
                                             const int* __restrict__ bsum, int n) {
    int i = blockIdx.x * 256 + threadIdx.x;
    if (i < n) offs[i] += bsum[i >> 10];
    if (i == 0) offs[n] = N_EDGES;
}

__global__ __launch_bounds__(256) void fill_k(const int* __restrict__ erow,
                                              const int* __restrict__ ecol,
                                              const int* __restrict__ offs,
                                              int* __restrict__ cursor,
                                              int* __restrict__ esrc,
                                              float* __restrict__ enorm,
                                              const float* __restrict__ disv) {
    int e = blockIdx.x * 256 + threadIdx.x;
    if (e >= N_EDGES) return;
    int r = erow[e], c = ecol[e];
    int pos = offs[c] + atomicAdd(&cursor[c], 1);
    esrc[pos] = r;
    enorm[pos] = disv[r] * disv[c];
}

// ---- GEMM: C[M,64] = A[M,K] @ B[K,64] + bias, fp32, BM=64 BN=64 BK=32 ----
__global__ __launch_bounds__(256) void gemm_n64(const float* __restrict__ A,
                                                const float* __restrict__ B,
                                                const float* __restrict__ bias,
                                                float* __restrict__ C,
                                                int M, int K) {
    __shared__ float As[32][68];   // transposed [k][m], padded
    __shared__ float Bs[32][64];   // [k][n]
    int t = threadIdx.x;
    int tr = t >> 4, tc = t & 15;
    int m0 = tr * 4, n0 = tc * 4;
    int blockRow = blockIdx.x * 64;
    float acc[4][4];
#pragma unroll
    for (int i = 0; i < 4; i++)
#pragma unroll
        for (int j = 0; j < 4; j++) acc[i][j] = 0.f;
    float bv[4];
#pragma unroll
    for (int j = 0; j < 4; j++) bv[j] = bias[n0 + j];

    for (int kk = 0; kk < K; kk += 32) {
        // stage A tile (64 rows x 32 k), transposed into As[k][m]
#pragma unroll
        for (int u = 0; u < 2; u++) {
            int idx4 = t * 2 + u;          // 0..511
            int m = idx4 >> 3;             // 0..63
            int k4 = (idx4 & 7) * 4;       // 0,4,..,28
            int row = blockRow + m;
            float4 v;
            if (row < M) v = *(const float4*)(A + (size_t)row * K + kk + k4);
            else v = make_float4(0.f, 0.f, 0.f, 0.f);
            As[k4 + 0][m] = v.x;
            As[k4 + 1][m] = v.y;
            As[k4 + 2][m] = v.z;
            As[k4 + 3][m] = v.w;
        }
        // stage B tile (32 k x 64 n)
#pragma unroll
        for (int u = 0; u < 2; u++) {
            int idx4 = t * 2 + u;          // 0..511
            int kr = idx4 >> 4;            // 0..31
            int nc = (idx4 & 15) * 4;
            *(float4*)&Bs[kr][nc] = *(const float4*)(B + (size_t)(kk + kr) * 64 + nc);
        }
        __syncthreads();
#pragma unroll
        for (int k = 0; k < 32; k++) {
            float4 a = *(const float4*)&As[k][m0];
            float4 b = *(const float4*)&Bs[k][n0];
            acc[0][0] = fmaf(a.x, b.x, acc[0][0]);
            acc[0][1] = fmaf(a.x, b.y, acc[0][1]);
            acc[0][2] = fmaf(a.x, b.z, acc[0][2]);
            acc[0][3] = fmaf(a.x, b.w, acc[0][3]);
            acc[1][0] = fmaf(a.y, b.x, acc[1][0]);
            acc[1][1] = fmaf(a.y, b.y, acc[1][1]);
            acc[1][2] = fmaf(a.y, b.z, acc[1][2]);
            acc[1][3] = fmaf(a.y, b.w, acc[1][3]);
            acc[2][0] = fmaf(a.z, b.x, acc[2][0]);
            acc[2][1] = fmaf(a.z, b.y, acc[2][1]);
            acc[2][2] = fmaf(a.z, b.z, acc[2][2]);
            acc[2][3] = fmaf(a.z, b.w, acc[2][3]);
            acc[3][0] = fmaf(a.w, b.x, acc[3][0]);
            acc[3][1] = fmaf(a.w, b.y, acc[3][1]);
            acc[3][2] = fmaf(a.w, b.z, acc[3][2]);
            acc[3][3] = fmaf(a.w, b.w, acc[3][3]);
        }
        __syncthreads();
    }
#pragma unroll
    for (int i = 0; i < 4; i++) {
        int row = blockRow + m0 + i;
        if (row < M) {
            float4 o = make_float4(acc[i][0] + bv[0], acc[i][1] + bv[1],
                                   acc[i][2] + bv[2], acc[i][3] + bv[3]);
            *(float4*)&C[(size_t)row * 64 + n0] = o;
        }
    }
}

// ---- aggregation: one wave per node, lane = feature ----
__global__ __launch_bounds__(256) void agg_k(const float* __restrict__ H,
                                             const int* __restrict__ offs,
                                             const int* __restrict__ esrc,
                                             const float* __restrict__ enorm,
                                             const float* __restrict__ disv,
                                             float* __restrict__ out,
                                             int do_relu) {
    int wv = (blockIdx.x * 256 + threadIdx.x) >> 6;
    int lane = threadIdx.x & 63;
    if (wv >= N_NODES) return;
    float d = disv[wv];
    float acc = d * d * H[(size_t)wv * 64 + lane];   // self loop
    int s = offs[wv], e = offs[wv + 1];
    for (int i = s; i < e; i++) {
        int src = esrc[i];
        float w = enorm[i];
        acc = fmaf(w, H[(size_t)src * 64 + lane], acc);
    }
    if (do_relu) acc = fmaxf(acc, 0.f);
    out[(size_t)wv * 64 + lane] = acc;
}

// ---- output: logits = H @ Wo + bo, then log_softmax; one wave per row ----
__global__ __launch_bounds__(256) void out_k(const float* __restrict__ H,
                                             const float* __restrict__ Wo,
                                             const float* __restrict__ bo,
                                             float* __restrict__ out) {
    __shared__ float Wl[HIDDEN * N_CLASSES];
    __shared__ float bl[N_CLASSES];
    for (int i = threadIdx.x; i < HIDDEN * N_CLASSES; i += 256) Wl[i] = Wo[i];
    if (threadIdx.x < N_CLASSES) bl[threadIdx.x] = bo[threadIdx.x];
    __syncthreads();
    int wv = (blockIdx.x * 256 + threadIdx.x) >> 6;
    int lane = threadIdx.x & 63;
    if (wv >= N_NODES) return;
    float hv = H[(size_t)wv * 64 + lane];
    float acc = (lane < N_CLASSES) ? bl[lane] : -1e30f;
#pragma unroll
    for (int k = 0; k < HIDDEN; k++) {
        float xb = __shfl(hv, k);
        if (lane < N_CLASSES) acc = fmaf(xb, Wl[k * N_CLASSES + lane], acc);
    }
    // wave-wide max
    float mx = acc;
#pragma unroll
    for (int d = 32; d; d >>= 1) mx = fmaxf(mx, __shfl_xor(mx, d));
    float ex = (lane < N_CLASSES) ? expf(acc - mx) : 0.f;
    float sm = ex;
#pragma unroll
    for (int d = 32; d; d >>= 1) sm += __shfl_xor(sm, d);
    if (lane < N_CLASSES)
        out[(size_t)wv * N_CLASSES + lane] = acc - mx - logf(sm);
}

extern "C" void kernel_launch(void* const* d_in, const int* in_sizes, int n_in,
                              void* d_out, int out_size, void* d_ws, size_t ws_size,
                              hipStream_t stream) {
    const float* x  = (const float*)d_in[0];
    const float* W1 = (const float*)d_in[1];
    const float* b1 = (const float*)d_in[2];
    const float* W2 = (const float*)d_in[3];
    const float* b2 = (const float*)d_in[4];
    const float* Wo = (const float*)d_in[5];
    const float* bo = (const float*)d_in[6];
    const int* ei   = (const int*)d_in[7];
    const int* erow = ei;
    const int* ecol = ei + N_EDGES;

    char* ws = (char*)d_ws;
    float* h_a    = (float*)(ws + OFF_HA);
    float* h_b    = (float*)(ws + OFF_HB);
    int*   cnt_r  = (int*)(ws + OFF_CNTR);
    int*   cnt_c  = (int*)(ws + OFF_CNTC);
    int*   cursor = (int*)(ws + OFF_CUR);
    float* disv   = (float*)(ws + OFF_DIS);
    int*   offs   = (int*)(ws + OFF_OFFS);
    int*   bsum   = (int*)(ws + OFF_BSUM);
    int*   esrc   = (int*)(ws + OFF_ESRC);
    float* enorm  = (float*)(ws + OFF_ENRM);
    float* outp   = (float*)d_out;

    // zero cnt_row + cnt_col + cursor (contiguous 150000 ints)
    zero_i32<<<(150000 + 255) / 256, 256, 0, stream>>>(cnt_r, 150000);
    count_k<<<N_EDGES / 256, 256, 0, stream>>>(erow, ecol, cnt_r, cnt_c);
    dis_k<<<(N_NODES + 255) / 256, 256, 0, stream>>>(cnt_r, disv);
    scan1<<<49, 256, 0, stream>>>(cnt_c, offs, bsum, N_NODES);
    scan2<<<1, 64, 0, stream>>>(bsum, 49);
    scan3<<<(N_NODES + 255) / 256, 256, 0, stream>>>(offs, bsum, N_NODES);
    fill_k<<<N_EDGES / 256, 256, 0, stream>>>(erow, ecol, offs, cursor, esrc, enorm, disv);

    // conv1: lin -> aggregate(+relu)
    gemm_n64<<<(N_NODES + 63) / 64, 256, 0, stream>>>(x, W1, b1, h_a, N_NODES, N_IN);
    agg_k<<<(N_NODES + 3) / 4, 256, 0, stream>>>(h_a, offs, esrc, enorm, disv, h_b, 1);
    // conv2
    gemm_n64<<<(N_NODES + 63) / 64, 256, 0, stream>>>(h_b, W2, b2, h_a, N_NODES, HIDDEN);
    agg_k<<<(N_NODES + 3) / 4, 256, 0, stream>>>(h_a, offs, esrc, enorm, disv, h_b, 0);
    // output head + log_softmax
    out_k<<<(N_NODES + 3) / 4, 256, 0, stream>>>(h_b, Wo, bo, outp);
}

// Round 2
// 319.031 us; speedup vs baseline: 1.2727x; 1.2727x over previous
//
#include <hip/hip_runtime.h>
#include <cstdint>

// Problem constants (from reference)
#define N_NODES   50000
#define N_IN      512
#define HIDDEN    64
#define N_CLASSES 40
#define N_EDGES   800000

// Workspace layout (byte offsets, all 16B-aligned)
#define OFF_HA   0u            // 50000*64*4 = 12,800,000
#define OFF_HB   12800000u     // 12,800,000
#define OFF_CNTR 25600000u     // 50000 ints (deg counts over row)
#define OFF_CNTC 25800000u     // 50000 ints (counts over col)
#define OFF_CUR  26000000u     // 50000 ints (fill cursors)
#define OFF_DIS  26200000u     // 50000 floats (deg^-0.5)
#define OFF_OFFS 26400000u     // 50001 ints (CSR offsets)
#define OFF_BSUM 26600704u     // 49 ints (scan block sums)
#define OFF_EDATA 26601216u    // 800000 int2 {src, norm-bits} = 6.4 MB
// total ~33.0 MB

__global__ __launch_bounds__(256) void zero_i32(int* p, int n) {
    int i = blockIdx.x * 256 + threadIdx.x;
    if (i < n) p[i] = 0;
}

__global__ __launch_bounds__(256) void count_k(const int* __restrict__ erow,
                                               const int* __restrict__ ecol,
                                               int* __restrict__ cnt_row,
                                               int* __restrict__ cnt_col) {
    int e = blockIdx.x * 256 + threadIdx.x;
    if (e >= N_EDGES) return;
    atomicAdd(&cnt_row[erow[e]], 1);
    atomicAdd(&cnt_col[ecol[e]], 1);
}

__global__ __launch_bounds__(256) void dis_k(const int* __restrict__ cnt_row,
                                             float* __restrict__ disv) {
    int i = blockIdx.x * 256 + threadIdx.x;
    if (i >= N_NODES) return;
    disv[i] = rsqrtf((float)(cnt_row[i] + 1));   // +1 self loop
}

// ---- exclusive scan of cnt_col (50000) -> offs ----
__global__ __launch_bounds__(256) void scan1(const int* __restrict__ in,
                                             int* __restrict__ out,
                                             int* __restrict__ bsum, int n) {
    int t = threadIdx.x;
    int base = blockIdx.x * 1024;
    int g = base + t * 4;
    int v[4];
#pragma unroll
    for (int i = 0; i < 4; i++) v[i] = (g + i < n) ? in[g + i] : 0;
    int s = v[0] + v[1] + v[2] + v[3];
    int lane = t & 63, wid = t >> 6;
    int x = s;
#pragma unroll
    for (int d = 1; d < 64; d <<= 1) {
        int y = __shfl_up(x, d);
        if (lane >= d) x += y;
    }
    __shared__ int wt[4];
    if (lane == 63) wt[wid] = x;
    __syncthreads();
    int wo = 0;
    for (int w = 0; w < wid; w++) wo += wt[w];
    int run = wo + x - s;   // exclusive prefix of this thread's 4 elems
#pragma unroll
    for (int i = 0; i < 4; i++) {
        if (g + i < n) out[g + i] = run;
        run += v[i];
    }
    if (t == 255) bsum[blockIdx.x] = wo + x;
}

__global__ void scan2(int* bsum, int nb) {
    int lane = threadIdx.x;   // launched with 64 threads
    int v = (lane < nb) ? bsum[lane] : 0;
    int x = v;
#pragma unroll
    for (int d = 1; d < 64; d <<= 1) {
        int y = __shfl_up(x, d);
        if (lane >= d) x += y;
    }
    if (lane < nb) bsum[lane] = x - v;   // exclusive
}

__global__ __launch_bounds__(256) void scan3(int* __restrict__ offs,
                                             const int* __restrict__ bsum, int n) {
    int i = blockIdx.x * 256 + threadIdx.x;
    if (i < n) offs[i] += bsum[i >> 10];
    if (i == 0) offs[n] = N_EDGES;
}

__global__ __launch_bounds__(256) void fill_k(const int* __restrict__ erow,
                                              const int* __restrict__ ecol,
                                              const int* __restrict__ offs,
                                              int* __restrict__ cursor,
                                              int2* __restrict__ edata,
                                              const float* __restrict__ disv) {
    int e = blockIdx.x * 256 + threadIdx.x;
    if (e >= N_EDGES) return;
    int r = erow[e], c = ecol[e];
    int pos = offs[c] + atomicAdd(&cursor[c], 1);
    edata[pos] = make_int2(r, __float_as_int(disv[r] * disv[c]));
}

// ---- GEMM: C[M,64] = A[M,K] @ B[K,64] + bias, fp32, BM=64 BN=64 BK=32 ----
__global__ __launch_bounds__(256) void gemm_n64(const float* __restrict__ A,
                                                const float* __restrict__ B,
                                                const float* __restrict__ bias,
                                                float* __restrict__ C,
                                                int M, int K) {
    __shared__ float As[32][68];   // transposed [k][m], padded
    __shared__ float Bs[32][64];   // [k][n]
    int t = threadIdx.x;
    int tr = t >> 4, tc = t & 15;
    int m0 = tr * 4, n0 = tc * 4;
    int blockRow = blockIdx.x * 64;
    float acc[4][4];
#pragma unroll
    for (int i = 0; i < 4; i++)
#pragma unroll
        for (int j = 0; j < 4; j++) acc[i][j] = 0.f;
    float bv[4];
#pragma unroll
    for (int j = 0; j < 4; j++) bv[j] = bias[n0 + j];

    for (int kk = 0; kk < K; kk += 32) {
        // stage A tile (64 rows x 32 k), transposed into As[k][m]
#pragma unroll
        for (int u = 0; u < 2; u++) {
            int idx4 = t * 2 + u;          // 0..511
            int m = idx4 >> 3;             // 0..63
            int k4 = (idx4 & 7) * 4;       // 0,4,..,28
            int row = blockRow + m;
            float4 v;
            if (row < M) v = *(const float4*)(A + (size_t)row * K + kk + k4);
            else v = make_float4(0.f, 0.f, 0.f, 0.f);
            As[k4 + 0][m] = v.x;
            As[k4 + 1][m] = v.y;
            As[k4 + 2][m] = v.z;
            As[k4 + 3][m] = v.w;
        }
        // stage B tile (32 k x 64 n)
#pragma unroll
        for (int u = 0; u < 2; u++) {
            int idx4 = t * 2 + u;          // 0..511
            int kr = idx4 >> 4;            // 0..31
            int nc = (idx4 & 15) * 4;
            *(float4*)&Bs[kr][nc] = *(const float4*)(B + (size_t)(kk + kr) * 64 + nc);
        }
        __syncthreads();
#pragma unroll
        for (int k = 0; k < 32; k++) {
            float4 a = *(const float4*)&As[k][m0];
            float4 b = *(const float4*)&Bs[k][n0];
            acc[0][0] = fmaf(a.x, b.x, acc[0][0]);
            acc[0][1] = fmaf(a.x, b.y, acc[0][1]);
            acc[0][2] = fmaf(a.x, b.z, acc[0][2]);
            acc[0][3] = fmaf(a.x, b.w, acc[0][3]);
            acc[1][0] = fmaf(a.y, b.x, acc[1][0]);
            acc[1][1] = fmaf(a.y, b.y, acc[1][1]);
            acc[1][2] = fmaf(a.y, b.z, acc[1][2]);
            acc[1][3] = fmaf(a.y, b.w, acc[1][3]);
            acc[2][0] = fmaf(a.z, b.x, acc[2][0]);
            acc[2][1] = fmaf(a.z, b.y, acc[2][1]);
            acc[2][2] = fmaf(a.z, b.z, acc[2][2]);
            acc[2][3] = fmaf(a.z, b.w, acc[2][3]);
            acc[3][0] = fmaf(a.w, b.x, acc[3][0]);
            acc[3][1] = fmaf(a.w, b.y, acc[3][1]);
            acc[3][2] = fmaf(a.w, b.z, acc[3][2]);
            acc[3][3] = fmaf(a.w, b.w, acc[3][3]);
        }
        __syncthreads();
    }
#pragma unroll
    for (int i = 0; i < 4; i++) {
        int row = blockRow + m0 + i;
        if (row < M) {
            float4 o = make_float4(acc[i][0] + bv[0], acc[i][1] + bv[1],
                                   acc[i][2] + bv[2], acc[i][3] + bv[3]);
            *(float4*)&C[(size_t)row * 64 + n0] = o;
        }
    }
}

// ---- aggregation: one wave per node, lane = feature, 8-wide batched gather ----
__global__ __launch_bounds__(256) void agg_k(const float* __restrict__ H,
                                             const int* __restrict__ offs,
                                             const int2* __restrict__ edata,
                                             const float* __restrict__ disv,
                                             float* __restrict__ out,
                                             int do_relu) {
    int wv = (blockIdx.x * 256 + threadIdx.x) >> 6;
    int lane = threadIdx.x & 63;
    if (wv >= N_NODES) return;
    float d = disv[wv];
    float acc = d * d * H[(size_t)wv * 64 + lane];   // self loop
    int s = offs[wv], e = offs[wv + 1];
    int i = s;
    // full batches of 8: all 8 H-row loads issued independently (MLP)
    for (; i + 8 <= e; i += 8) {
        int2 ed[8];
        float hv[8];
#pragma unroll
        for (int u = 0; u < 8; u++) ed[u] = edata[i + u];
#pragma unroll
        for (int u = 0; u < 8; u++) hv[u] = H[(size_t)ed[u].x * 64 + lane];
#pragma unroll
        for (int u = 0; u < 8; u++) acc = fmaf(__int_as_float(ed[u].y), hv[u], acc);
    }
    // remainder: clamped predicated batch (still parallel loads, no serial tail)
    int rem = e - i;
    if (rem > 0) {
        int2 ed[8];
        float hv[8];
#pragma unroll
        for (int u = 0; u < 8; u++) ed[u] = edata[(u < rem) ? (i + u) : i];
#pragma unroll
        for (int u = 0; u < 8; u++) hv[u] = H[(size_t)ed[u].x * 64 + lane];
#pragma unroll
        for (int u = 0; u < 8; u++) {
            float w = (u < rem) ? __int_as_float(ed[u].y) : 0.f;
            acc = fmaf(w, hv[u], acc);
        }
    }
    if (do_relu) acc = fmaxf(acc, 0.f);
    out[(size_t)wv * 64 + lane] = acc;
}

// ---- output: logits = H @ Wo + bo, then log_softmax; one wave per row ----
__global__ __launch_bounds__(256) void out_k(const float* __restrict__ H,
                                             const float* __restrict__ Wo,
                                             const float* __restrict__ bo,
                                             float* __restrict__ out) {
    __shared__ float Wl[HIDDEN * N_CLASSES];
    __shared__ float bl[N_CLASSES];
    for (int i = threadIdx.x; i < HIDDEN * N_CLASSES; i += 256) Wl[i] = Wo[i];
    if (threadIdx.x < N_CLASSES) bl[threadIdx.x] = bo[threadIdx.x];
    __syncthreads();
    int wv = (blockIdx.x * 256 + threadIdx.x) >> 6;
    int lane = threadIdx.x & 63;
    if (wv >= N_NODES) return;
    float hv = H[(size_t)wv * 64 + lane];
    float acc = (lane < N_CLASSES) ? bl[lane] : -1e30f;
#pragma unroll
    for (int k = 0; k < HIDDEN; k++) {
        float xb = __shfl(hv, k);
        if (lane < N_CLASSES) acc = fmaf(xb, Wl[k * N_CLASSES + lane], acc);
    }
    // wave-wide max
    float mx = acc;
#pragma unroll
    for (int d = 32; d; d >>= 1) mx = fmaxf(mx, __shfl_xor(mx, d));
    float ex = (lane < N_CLASSES) ? expf(acc - mx) : 0.f;
    float sm = ex;
#pragma unroll
    for (int d = 32; d; d >>= 1) sm += __shfl_xor(sm, d);
    if (lane < N_CLASSES)
        out[(size_t)wv * N_CLASSES + lane] = acc - mx - logf(sm);
}

extern "C" void kernel_launch(void* const* d_in, const int* in_sizes, int n_in,
                              void* d_out, int out_size, void* d_ws, size_t ws_size,
                              hipStream_t stream) {
    const float* x  = (const float*)d_in[0];
    const float* W1 = (const float*)d_in[1];
    const float* b1 = (const float*)d_in[2];
    const float* W2 = (const float*)d_in[3];
    const float* b2 = (const float*)d_in[4];
    const float* Wo = (const float*)d_in[5];
    const float* bo = (const float*)d_in[6];
    const int* ei   = (const int*)d_in[7];
    const int* erow = ei;
    const int* ecol = ei + N_EDGES;

    char* ws = (char*)d_ws;
    float* h_a    = (float*)(ws + OFF_HA);
    float* h_b    = (float*)(ws + OFF_HB);
    int*   cnt_r  = (int*)(ws + OFF_CNTR);
    int*   cnt_c  = (int*)(ws + OFF_CNTC);
    int*   cursor = (int*)(ws + OFF_CUR);
    float* disv   = (float*)(ws + OFF_DIS);
    int*   offs   = (int*)(ws + OFF_OFFS);
    int*   bsum   = (int*)(ws + OFF_BSUM);
    int2*  edata  = (int2*)(ws + OFF_EDATA);
    float* outp   = (float*)d_out;

    // zero cnt_row + cnt_col + cursor (contiguous 150000 ints)
    zero_i32<<<(150000 + 255) / 256, 256, 0, stream>>>(cnt_r, 150000);
    count_k<<<N_EDGES / 256, 256, 0, stream>>>(erow, ecol, cnt_r, cnt_c);
    dis_k<<<(N_NODES + 255) / 256, 256, 0, stream>>>(cnt_r, disv);
    scan1<<<49, 256, 0, stream>>>(cnt_c, offs, bsum, N_NODES);
    scan2<<<1, 64, 0, stream>>>(bsum, 49);
    scan3<<<(N_NODES + 255) / 256, 256, 0, stream>>>(offs, bsum, N_NODES);
    fill_k<<<N_EDGES / 256, 256, 0, stream>>>(erow, ecol, offs, cursor, edata, disv);

    // conv1: lin -> aggregate(+relu)
    gemm_n64<<<(N_NODES + 63) / 64, 256, 0, stream>>>(x, W1, b1, h_a, N_NODES, N_IN);
    agg_k<<<(N_NODES + 3) / 4, 256, 0, stream>>>(h_a, offs, edata, disv, h_b, 1);
    // conv2
    gemm_n64<<<(N_NODES + 63) / 64, 256, 0, stream>>>(h_b, W2, b2, h_a, N_NODES, HIDDEN);
    agg_k<<<(N_NODES + 3) / 4, 256, 0, stream>>>(h_a, offs, edata, disv, h_b, 0);
    // output head + log_softmax
    out_k<<<(N_NODES + 3) / 4, 256, 0, stream>>>(h_b, Wo, bo, outp);
}

// Round 3
// 283.049 us; speedup vs baseline: 1.4345x; 1.1271x over previous
//
#include <hip/hip_runtime.h>
#include <cstdint>

// Problem constants (from reference)
#define N_NODES   50000
#define N_IN      512
#define HIDDEN    64
#define N_CLASSES 40
#define N_EDGES   800000

// Workspace layout (byte offsets, all 16B-aligned)
#define OFF_HA   0u            // 50000*64*4 = 12,800,000
#define OFF_HB   12800000u     // 12,800,000
#define OFF_CNTR 25600000u     // 50000 ints (deg counts over row)
#define OFF_CNTC 25800000u     // 50000 ints (counts over col); DEAD after scan1 ->
                               //   reused for W1T/W2T (72 KB < 200 KB)
#define OFF_CUR  26000000u     // 50000 ints (fill cursors)
#define OFF_DIS  26200000u     // 50000 floats (deg^-0.5)
#define OFF_OFFS 26400000u     // 50001 ints (CSR offsets)
#define OFF_BSUM 26600704u     // 49 ints (scan block sums)
#define OFF_EDATA 26601216u    // 800000 int2 {src, norm-bits} = 6.4 MB
#define OFF_W1T  25800000u     // 64*512 ushort bf16 = 65536 B (overlays cnt_col)
#define OFF_W2T  25865536u     // 64*64 ushort bf16 = 8192 B
// total ~33.0 MB (unchanged)

typedef __attribute__((ext_vector_type(8))) short short8_t;
typedef __attribute__((ext_vector_type(4))) float f32x4;

__device__ __forceinline__ ushort f2bf(float f) {
    uint u = __float_as_uint(f);
    uint r = (u + 0x7FFFu + ((u >> 16) & 1u)) >> 16;   // RNE
    return (ushort)r;
}

__global__ __launch_bounds__(256) void zero_i32(int* p, int n) {
    int i = blockIdx.x * 256 + threadIdx.x;
    if (i < n) p[i] = 0;
}

__global__ __launch_bounds__(256) void count_k(const int* __restrict__ erow,
                                               const int* __restrict__ ecol,
                                               int* __restrict__ cnt_row,
                                               int* __restrict__ cnt_col) {
    int e = blockIdx.x * 256 + threadIdx.x;
    if (e >= N_EDGES) return;
    atomicAdd(&cnt_row[erow[e]], 1);
    atomicAdd(&cnt_col[ecol[e]], 1);
}

__global__ __launch_bounds__(256) void dis_k(const int* __restrict__ cnt_row,
                                             float* __restrict__ disv) {
    int i = blockIdx.x * 256 + threadIdx.x;
    if (i >= N_NODES) return;
    disv[i] = rsqrtf((float)(cnt_row[i] + 1));   // +1 self loop
}

// ---- exclusive scan of cnt_col (50000) -> offs ----
__global__ __launch_bounds__(256) void scan1(const int* __restrict__ in,
                                             int* __restrict__ out,
                                             int* __restrict__ bsum, int n) {
    int t = threadIdx.x;
    int base = blockIdx.x * 1024;
    int g = base + t * 4;
    int v[4];
#pragma unroll
    for (int i = 0; i < 4; i++) v[i] = (g + i < n) ? in[g + i] : 0;
    int s = v[0] + v[1] + v[2] + v[3];
    int lane = t & 63, wid = t >> 6;
    int x = s;
#pragma unroll
    for (int d = 1; d < 64; d <<= 1) {
        int y = __shfl_up(x, d);
        if (lane >= d) x += y;
    }
    __shared__ int wt[4];
    if (lane == 63) wt[wid] = x;
    __syncthreads();
    int wo = 0;
    for (int w = 0; w < wid; w++) wo += wt[w];
    int run = wo + x - s;   // exclusive prefix of this thread's 4 elems
#pragma unroll
    for (int i = 0; i < 4; i++) {
        if (g + i < n) out[g + i] = run;
        run += v[i];
    }
    if (t == 255) bsum[blockIdx.x] = wo + x;
}

__global__ void scan2(int* bsum, int nb) {
    int lane = threadIdx.x;   // launched with 64 threads
    int v = (lane < nb) ? bsum[lane] : 0;
    int x = v;
#pragma unroll
    for (int d = 1; d < 64; d <<= 1) {
        int y = __shfl_up(x, d);
        if (lane >= d) x += y;
    }
    if (lane < nb) bsum[lane] = x - v;   // exclusive
}

__global__ __launch_bounds__(256) void scan3(int* __restrict__ offs,
                                             const int* __restrict__ bsum, int n) {
    int i = blockIdx.x * 256 + threadIdx.x;
    if (i < n) offs[i] += bsum[i >> 10];
    if (i == 0) offs[n] = N_EDGES;
}

__global__ __launch_bounds__(256) void fill_k(const int* __restrict__ erow,
                                              const int* __restrict__ ecol,
                                              const int* __restrict__ offs,
                                              int* __restrict__ cursor,
                                              int2* __restrict__ edata,
                                              const float* __restrict__ disv) {
    int e = blockIdx.x * 256 + threadIdx.x;
    if (e >= N_EDGES) return;
    int r = erow[e], c = ecol[e];
    int pos = offs[c] + atomicAdd(&cursor[c], 1);
    edata[pos] = make_int2(r, __float_as_int(disv[r] * disv[c]));
}

// ---- transpose + cast W[K][64] fp32 -> WT[64][K] bf16 ----
__global__ __launch_bounds__(256) void transpose_w(const float* __restrict__ W,
                                                   ushort* __restrict__ WT, int K) {
    int i = blockIdx.x * 256 + threadIdx.x;
    if (i >= K * 64) return;
    int k = i >> 6, n = i & 63;
    WT[n * K + k] = f2bf(W[i]);
}

// ---- MFMA GEMM: C[M,64] = A[M,K](fp32) @ WT[64,K](bf16,transposed) + bias ----
// BM=64 BN=64 BK=64, 256 threads = 4 waves, each wave owns a 32x32 sub-tile.
__global__ __launch_bounds__(256) void gemm_mfma(const float* __restrict__ A,
                                                 const ushort* __restrict__ WT,
                                                 const float* __restrict__ bias,
                                                 float* __restrict__ C,
                                                 int M, int K) {
    __shared__ ushort Asb[64][72];   // [m][k], +8 pad
    __shared__ ushort Bsb[64][72];   // [n][k], +8 pad
    int t = threadIdx.x;
    int w = t >> 6, lane = t & 63;
    int wm = w >> 1, wn = w & 1;           // 2x2 wave grid
    int lr = lane & 15, lg = lane >> 4;    // frag row/col, k-group
    int blockRow = blockIdx.x * 64;

    f32x4 acc[2][2];
#pragma unroll
    for (int i = 0; i < 2; i++)
#pragma unroll
        for (int j = 0; j < 2; j++) acc[i][j] = (f32x4){0.f, 0.f, 0.f, 0.f};

    for (int kk = 0; kk < K; kk += 64) {
        // stage A: 64 rows x 64 k, fp32 -> bf16
#pragma unroll
        for (int u = 0; u < 2; u++) {
            int idx = t + u * 256;         // 0..511
            int m = idx >> 3;              // 0..63
            int k8 = (idx & 7) * 8;        // 0..56
            int row = blockRow + m;
            float4 a0, a1;
            if (row < M) {
                const float* p = A + (size_t)row * K + kk + k8;
                a0 = *(const float4*)p;
                a1 = *(const float4*)(p + 4);
            } else {
                a0 = make_float4(0.f, 0.f, 0.f, 0.f);
                a1 = a0;
            }
            short8_t s;
            s[0] = (short)f2bf(a0.x); s[1] = (short)f2bf(a0.y);
            s[2] = (short)f2bf(a0.z); s[3] = (short)f2bf(a0.w);
            s[4] = (short)f2bf(a1.x); s[5] = (short)f2bf(a1.y);
            s[6] = (short)f2bf(a1.z); s[7] = (short)f2bf(a1.w);
            *(short8_t*)&Asb[m][k8] = s;
        }
        // stage B: 64 n-rows x 64 k, already bf16 transposed
#pragma unroll
        for (int u = 0; u < 2; u++) {
            int idx = t + u * 256;
            int n = idx >> 3;
            int k8 = (idx & 7) * 8;
            short8_t v = *(const short8_t*)(WT + (size_t)n * K + kk + k8);
            *(short8_t*)&Bsb[n][k8] = v;
        }
        __syncthreads();
#pragma unroll
        for (int ks = 0; ks < 2; ks++) {
            int k0 = ks * 32 + lg * 8;
            short8_t af[2], bf[2];
#pragma unroll
            for (int mi = 0; mi < 2; mi++)
                af[mi] = *(const short8_t*)&Asb[wm * 32 + mi * 16 + lr][k0];
#pragma unroll
            for (int ni = 0; ni < 2; ni++)
                bf[ni] = *(const short8_t*)&Bsb[wn * 32 + ni * 16 + lr][k0];
#pragma unroll
            for (int mi = 0; mi < 2; mi++)
#pragma unroll
                for (int ni = 0; ni < 2; ni++)
                    acc[mi][ni] = __builtin_amdgcn_mfma_f32_16x16x32_bf16(
                        af[mi], bf[ni], acc[mi][ni], 0, 0, 0);
        }
        __syncthreads();
    }
    // epilogue: D layout col=lane&15, row=(lane>>4)*4+reg
#pragma unroll
    for (int mi = 0; mi < 2; mi++) {
#pragma unroll
        for (int ni = 0; ni < 2; ni++) {
            int col = wn * 32 + ni * 16 + lr;
            float bv = bias[col];
#pragma unroll
            for (int r = 0; r < 4; r++) {
                int row = blockRow + wm * 32 + mi * 16 + lg * 4 + r;
                if (row < M) C[(size_t)row * 64 + col] = acc[mi][ni][r] + bv;
            }
        }
    }
}

// ---- aggregation: one wave per node, lane = feature, 8-wide batched gather ----
__global__ __launch_bounds__(256) void agg_k(const float* __restrict__ H,
                                             const int* __restrict__ offs,
                                             const int2* __restrict__ edata,
                                             const float* __restrict__ disv,
                                             float* __restrict__ out,
                                             int do_relu) {
    int wv = (blockIdx.x * 256 + threadIdx.x) >> 6;
    int lane = threadIdx.x & 63;
    if (wv >= N_NODES) return;
    float d = disv[wv];
    float acc = d * d * H[(size_t)wv * 64 + lane];   // self loop
    int s = offs[wv], e = offs[wv + 1];
    int i = s;
    // full batches of 8: all 8 H-row loads issued independently (MLP)
    for (; i + 8 <= e; i += 8) {
        int2 ed[8];
        float hv[8];
#pragma unroll
        for (int u = 0; u < 8; u++) ed[u] = edata[i + u];
#pragma unroll
        for (int u = 0; u < 8; u++) hv[u] = H[(size_t)ed[u].x * 64 + lane];
#pragma unroll
        for (int u = 0; u < 8; u++) acc = fmaf(__int_as_float(ed[u].y), hv[u], acc);
    }
    // remainder: clamped predicated batch (still parallel loads, no serial tail)
    int rem = e - i;
    if (rem > 0) {
        int2 ed[8];
        float hv[8];
#pragma unroll
        for (int u = 0; u < 8; u++) ed[u] = edata[(u < rem) ? (i + u) : i];
#pragma unroll
        for (int u = 0; u < 8; u++) hv[u] = H[(size_t)ed[u].x * 64 + lane];
#pragma unroll
        for (int u = 0; u < 8; u++) {
            float w = (u < rem) ? __int_as_float(ed[u].y) : 0.f;
            acc = fmaf(w, hv[u], acc);
        }
    }
    if (do_relu) acc = fmaxf(acc, 0.f);
    out[(size_t)wv * 64 + lane] = acc;
}

// ---- output: logits = H @ Wo + bo, then log_softmax; one wave per row ----
__global__ __launch_bounds__(256) void out_k(const float* __restrict__ H,
                                             const float* __restrict__ Wo,
                                             const float* __restrict__ bo,
                                             float* __restrict__ out) {
    __shared__ float Wl[HIDDEN * N_CLASSES];
    __shared__ float bl[N_CLASSES];
    for (int i = threadIdx.x; i < HIDDEN * N_CLASSES; i += 256) Wl[i] = Wo[i];
    if (threadIdx.x < N_CLASSES) bl[threadIdx.x] = bo[threadIdx.x];
    __syncthreads();
    int wv = (blockIdx.x * 256 + threadIdx.x) >> 6;
    int lane = threadIdx.x & 63;
    if (wv >= N_NODES) return;
    float hv = H[(size_t)wv * 64 + lane];
    float acc = (lane < N_CLASSES) ? bl[lane] : -1e30f;
#pragma unroll
    for (int k = 0; k < HIDDEN; k++) {
        float xb = __shfl(hv, k);
        if (lane < N_CLASSES) acc = fmaf(xb, Wl[k * N_CLASSES + lane], acc);
    }
    // wave-wide max
    float mx = acc;
#pragma unroll
    for (int d = 32; d; d >>= 1) mx = fmaxf(mx, __shfl_xor(mx, d));
    float ex = (lane < N_CLASSES) ? expf(acc - mx) : 0.f;
    float sm = ex;
#pragma unroll
    for (int d = 32; d; d >>= 1) sm += __shfl_xor(sm, d);
    if (lane < N_CLASSES)
        out[(size_t)wv * N_CLASSES + lane] = acc - mx - logf(sm);
}

extern "C" void kernel_launch(void* const* d_in, const int* in_sizes, int n_in,
                              void* d_out, int out_size, void* d_ws, size_t ws_size,
                              hipStream_t stream) {
    const float* x  = (const float*)d_in[0];
    const float* W1 = (const float*)d_in[1];
    const float* b1 = (const float*)d_in[2];
    const float* W2 = (const float*)d_in[3];
    const float* b2 = (const float*)d_in[4];
    const float* Wo = (const float*)d_in[5];
    const float* bo = (const float*)d_in[6];
    const int* ei   = (const int*)d_in[7];
    const int* erow = ei;
    const int* ecol = ei + N_EDGES;

    char* ws = (char*)d_ws;
    float* h_a    = (float*)(ws + OFF_HA);
    float* h_b    = (float*)(ws + OFF_HB);
    int*   cnt_r  = (int*)(ws + OFF_CNTR);
    int*   cnt_c  = (int*)(ws + OFF_CNTC);
    int*   cursor = (int*)(ws + OFF_CUR);
    float* disv   = (float*)(ws + OFF_DIS);
    int*   offs   = (int*)(ws + OFF_OFFS);
    int*   bsum   = (int*)(ws + OFF_BSUM);
    int2*  edata  = (int2*)(ws + OFF_EDATA);
    ushort* w1t   = (ushort*)(ws + OFF_W1T);   // overlays cnt_c (dead after scan1)
    ushort* w2t   = (ushort*)(ws + OFF_W2T);
    float* outp   = (float*)d_out;

    // zero cnt_row + cnt_col + cursor (contiguous 150000 ints)
    zero_i32<<<(150000 + 255) / 256, 256, 0, stream>>>(cnt_r, 150000);
    count_k<<<N_EDGES / 256, 256, 0, stream>>>(erow, ecol, cnt_r, cnt_c);
    dis_k<<<(N_NODES + 255) / 256, 256, 0, stream>>>(cnt_r, disv);
    scan1<<<49, 256, 0, stream>>>(cnt_c, offs, bsum, N_NODES);
    scan2<<<1, 64, 0, stream>>>(bsum, 49);
    scan3<<<(N_NODES + 255) / 256, 256, 0, stream>>>(offs, bsum, N_NODES);
    // cnt_c is dead now; transpose weights into its region
    transpose_w<<<(N_IN * 64 + 255) / 256, 256, 0, stream>>>(W1, w1t, N_IN);
    transpose_w<<<(HIDDEN * 64 + 255) / 256, 256, 0, stream>>>(W2, w2t, HIDDEN);
    fill_k<<<N_EDGES / 256, 256, 0, stream>>>(erow, ecol, offs, cursor, edata, disv);

    // conv1: lin (MFMA bf16) -> aggregate(+relu)
    gemm_mfma<<<(N_NODES + 63) / 64, 256, 0, stream>>>(x, w1t, b1, h_a, N_NODES, N_IN);
    agg_k<<<(N_NODES + 3) / 4, 256, 0, stream>>>(h_a, offs, edata, disv, h_b, 1);
    // conv2
    gemm_mfma<<<(N_NODES + 63) / 64, 256, 0, stream>>>(h_b, w2t, b2, h_a, N_NODES, HIDDEN);
    agg_k<<<(N_NODES + 3) / 4, 256, 0, stream>>>(h_a, offs, edata, disv, h_b, 0);
    // output head + log_softmax
    out_k<<<(N_NODES + 3) / 4, 256, 0, stream>>>(h_b, Wo, bo, outp);
}

// Round 4
// 190.943 us; speedup vs baseline: 2.1265x; 1.4824x over previous
//
#include <hip/hip_runtime.h>
#include <cstdint>

// Problem constants (from reference)
#define N_NODES   50000
#define N_IN      512
#define HIDDEN    64
#define N_CLASSES 40
#define N_EDGES   800000

// Radix build parameters
#define G_BLOCKS  200                 // blocks in hist/scatter passes
#define EPB       4000                // edges per block (G_BLOCKS*EPB == N_EDGES)
#define NBINS     196                 // ceil(50000/256), bin = node >> 8
#define SCAN_N    (NBINS * G_BLOCKS)  // 39200

// Workspace layout (byte offsets, 16B-aligned)
#define OFF_HA    0u          // 50000*64*4 = 12,800,000
#define OFF_HB    12800000u   // 12,800,000
#define OFF_DIS   25600000u   // 50000 floats = 200,000
#define OFF_OFFS  25800000u   // 50001 ints  = 200,004 (pad to 200,016)
#define OFF_HISTC 26000016u   // 39200 ints = 156,800
#define OFF_HISTR 26156816u   // 39200 ints = 156,800
#define OFF_BSUM  26313616u   // 64 ints = 256
#define OFF_COLS  26313872u   // 800000 u32 packed (r | c<<16) = 3,200,000
#define OFF_ROWS  29513872u   // 800000 ints = 3,200,000
#define OFF_ESRC  32713872u   // 800000 ints = 3,200,000
#define OFF_W1T   35913872u   // 64*512 bf16 = 65,536
#define OFF_W2T   35979408u   // 64*64 bf16 = 8,192
// total ~36.0 MB

typedef __attribute__((ext_vector_type(8))) short short8_t;
typedef __attribute__((ext_vector_type(4))) float f32x4;

__device__ __forceinline__ ushort f2bf(float f) {
    uint u = __float_as_uint(f);
    uint r = (u + 0x7FFFu + ((u >> 16) & 1u)) >> 16;   // RNE
    return (ushort)r;
}

// ---- stage 1: per-block coarse histograms (LDS only, no global atomics) ----
__global__ __launch_bounds__(256) void hist_k(const int* __restrict__ erow,
                                              const int* __restrict__ ecol,
                                              int* __restrict__ histC,
                                              int* __restrict__ histR) {
    __shared__ int hc[NBINS], hr[NBINS];
    int t = threadIdx.x, b = blockIdx.x;
    if (t < NBINS) { hc[t] = 0; hr[t] = 0; }
    __syncthreads();
    int s = b * EPB;
    for (int i = s + t; i < s + EPB; i += 256) {
        atomicAdd(&hc[ecol[i] >> 8], 1);
        atomicAdd(&hr[erow[i] >> 8], 1);
    }
    __syncthreads();
    if (t < NBINS) {
        histC[t * G_BLOCKS + b] = hc[t];   // [bin][block] layout for bin-major scan
        histR[t * G_BLOCKS + b] = hr[t];
    }
}

// ---- generic exclusive scan (1024 elems/block); in-place safe ----
__global__ __launch_bounds__(256) void scan1(const int* in, int* out,
                                             int* bsum, int n) {
    int t = threadIdx.x;
    int g = blockIdx.x * 1024 + t * 4;
    int v[4];
#pragma unroll
    for (int i = 0; i < 4; i++) v[i] = (g + i < n) ? in[g + i] : 0;
    int s = v[0] + v[1] + v[2] + v[3];
    int lane = t & 63, wid = t >> 6;
    int x = s;
#pragma unroll
    for (int d = 1; d < 64; d <<= 1) {
        int y = __shfl_up(x, d);
        if (lane >= d) x += y;
    }
    __shared__ int wt[4];
    if (lane == 63) wt[wid] = x;
    __syncthreads();
    int wo = 0;
    for (int w = 0; w < wid; w++) wo += wt[w];
    int run = wo + x - s;
#pragma unroll
    for (int i = 0; i < 4; i++) {
        if (g + i < n) out[g + i] = run;
        run += v[i];
    }
    if (t == 255) bsum[blockIdx.x] = wo + x;
}

__global__ void scan2(int* bsum, int nb) {
    int lane = threadIdx.x;   // 64 threads
    int v = (lane < nb) ? bsum[lane] : 0;
    int x = v;
#pragma unroll
    for (int d = 1; d < 64; d <<= 1) {
        int y = __shfl_up(x, d);
        if (lane >= d) x += y;
    }
    if (lane < nb) bsum[lane] = x - v;   // exclusive
}

__global__ __launch_bounds__(256) void scan3(int* __restrict__ a,
                                             const int* __restrict__ bsum, int n) {
    int i = blockIdx.x * 256 + threadIdx.x;
    if (i < n) a[i] += bsum[i >> 10];
}

// ---- stage 3: radix scatter into bin-sorted order (LDS cursors) ----
__global__ __launch_bounds__(256) void scatter_k(const int* __restrict__ erow,
                                                 const int* __restrict__ ecol,
                                                 const int* __restrict__ scC,
                                                 const int* __restrict__ scR,
                                                 uint* __restrict__ colSorted,
                                                 int* __restrict__ rowSorted) {
    __shared__ int curC[NBINS], curR[NBINS];
    int t = threadIdx.x, b = blockIdx.x;
    if (t < NBINS) {
        curC[t] = scC[t * G_BLOCKS + b];
        curR[t] = scR[t * G_BLOCKS + b];
    }
    __syncthreads();
    int s = b * EPB;
    for (int i = s + t; i < s + EPB; i += 256) {
        int r = erow[i], c = ecol[i];
        int p = atomicAdd(&curC[c >> 8], 1);
        colSorted[p] = (uint)r | ((uint)c << 16);   // both < 50000 < 2^16
        int q = atomicAdd(&curR[r >> 8], 1);
        rowSorted[q] = r;
    }
}

// ---- stage 4a: fine row counts -> disv (deg^-0.5 with self loop) ----
__global__ __launch_bounds__(256) void fine_row(const int* __restrict__ rowSorted,
                                                const int* __restrict__ scR,
                                                float* __restrict__ disv) {
    __shared__ int cnt[256];
    int bin = blockIdx.x, t = threadIdx.x;
    int base = scR[bin * G_BLOCKS];
    int end  = (bin == NBINS - 1) ? N_EDGES : scR[(bin + 1) * G_BLOCKS];
    cnt[t] = 0;
    __syncthreads();
    for (int i = base + t; i < end; i += 256)
        atomicAdd(&cnt[rowSorted[i] & 255], 1);
    __syncthreads();
    int node = bin * 256 + t;
    if (node < N_NODES) disv[node] = rsqrtf((float)(cnt[t] + 1));
}

// ---- stage 4b: fine col pass -> offs (CSR) + esrc (final edge order) ----
__global__ __launch_bounds__(256) void fine_col(const uint* __restrict__ colSorted,
                                                const int* __restrict__ scC,
                                                int* __restrict__ offs,
                                                int* __restrict__ esrc) {
    __shared__ int cnt[256];
    __shared__ int excl[256];
    __shared__ int wt[4];
    int bin = blockIdx.x, t = threadIdx.x;
    int base = scC[bin * G_BLOCKS];
    int end  = (bin == NBINS - 1) ? N_EDGES : scC[(bin + 1) * G_BLOCKS];
    cnt[t] = 0;
    __syncthreads();
    for (int i = base + t; i < end; i += 256)
        atomicAdd(&cnt[(colSorted[i] >> 16) & 255], 1);
    __syncthreads();
    // exclusive scan of cnt[256] (one value per thread)
    int lane = t & 63, w = t >> 6;
    int v = cnt[t];
    int x = v;
#pragma unroll
    for (int d = 1; d < 64; d <<= 1) {
        int y = __shfl_up(x, d);
        if (lane >= d) x += y;
    }
    if (lane == 63) wt[w] = x;
    __syncthreads();
    int wo = 0;
    for (int u = 0; u < w; u++) wo += wt[u];
    excl[t] = wo + x - v;
    cnt[t] = 0;              // reuse as fill cursor
    int node = bin * 256 + t;
    if (node <= N_NODES) offs[node] = base + wo + x - v;  // sentinel at 50000 free
    __syncthreads();
    for (int i = base + t; i < end; i += 256) {
        uint pv = colSorted[i];
        int cl = (pv >> 16) & 255;
        int p = base + excl[cl] + atomicAdd(&cnt[cl], 1);
        esrc[p] = (int)(pv & 0xFFFFu);
    }
}

// ---- transpose + cast W[K][64] fp32 -> WT[64][K] bf16 ----
__global__ __launch_bounds__(256) void transpose_w(const float* __restrict__ W,
                                                   ushort* __restrict__ WT, int K) {
    int i = blockIdx.x * 256 + threadIdx.x;
    if (i >= K * 64) return;
    int k = i >> 6, n = i & 63;
    WT[n * K + k] = f2bf(W[i]);
}

// ---- MFMA GEMM: C[M,64] = A[M,K](fp32) @ WT[64,K](bf16,transposed) + bias ----
__global__ __launch_bounds__(256) void gemm_mfma(const float* __restrict__ A,
                                                 const ushort* __restrict__ WT,
                                                 const float* __restrict__ bias,
                                                 float* __restrict__ C,
                                                 int M, int K) {
    __shared__ ushort Asb[64][72];   // [m][k], +8 pad
    __shared__ ushort Bsb[64][72];   // [n][k], +8 pad
    int t = threadIdx.x;
    int w = t >> 6, lane = t & 63;
    int wm = w >> 1, wn = w & 1;           // 2x2 wave grid
    int lr = lane & 15, lg = lane >> 4;    // frag row, k-group
    int blockRow = blockIdx.x * 64;

    f32x4 acc[2][2];
#pragma unroll
    for (int i = 0; i < 2; i++)
#pragma unroll
        for (int j = 0; j < 2; j++) acc[i][j] = (f32x4){0.f, 0.f, 0.f, 0.f};

    for (int kk = 0; kk < K; kk += 64) {
#pragma unroll
        for (int u = 0; u < 2; u++) {
            int idx = t + u * 256;
            int m = idx >> 3;
            int k8 = (idx & 7) * 8;
            int row = blockRow + m;
            float4 a0, a1;
            if (row < M) {
                const float* p = A + (size_t)row * K + kk + k8;
                a0 = *(const float4*)p;
                a1 = *(const float4*)(p + 4);
            } else {
                a0 = make_float4(0.f, 0.f, 0.f, 0.f);
                a1 = a0;
            }
            short8_t s;
            s[0] = (short)f2bf(a0.x); s[1] = (short)f2bf(a0.y);
            s[2] = (short)f2bf(a0.z); s[3] = (short)f2bf(a0.w);
            s[4] = (short)f2bf(a1.x); s[5] = (short)f2bf(a1.y);
            s[6] = (short)f2bf(a1.z); s[7] = (short)f2bf(a1.w);
            *(short8_t*)&Asb[m][k8] = s;
        }
#pragma unroll
        for (int u = 0; u < 2; u++) {
            int idx = t + u * 256;
            int n = idx >> 3;
            int k8 = (idx & 7) * 8;
            short8_t vv = *(const short8_t*)(WT + (size_t)n * K + kk + k8);
            *(short8_t*)&Bsb[n][k8] = vv;
        }
        __syncthreads();
#pragma unroll
        for (int ks = 0; ks < 2; ks++) {
            int k0 = ks * 32 + lg * 8;
            short8_t af[2], bf[2];
#pragma unroll
            for (int mi = 0; mi < 2; mi++)
                af[mi] = *(const short8_t*)&Asb[wm * 32 + mi * 16 + lr][k0];
#pragma unroll
            for (int ni = 0; ni < 2; ni++)
                bf[ni] = *(const short8_t*)&Bsb[wn * 32 + ni * 16 + lr][k0];
#pragma unroll
            for (int mi = 0; mi < 2; mi++)
#pragma unroll
                for (int ni = 0; ni < 2; ni++)
                    acc[mi][ni] = __builtin_amdgcn_mfma_f32_16x16x32_bf16(
                        af[mi], bf[ni], acc[mi][ni], 0, 0, 0);
        }
        __syncthreads();
    }
#pragma unroll
    for (int mi = 0; mi < 2; mi++) {
#pragma unroll
        for (int ni = 0; ni < 2; ni++) {
            int col = wn * 32 + ni * 16 + lr;
            float bv = bias[col];
#pragma unroll
            for (int r = 0; r < 4; r++) {
                int row = blockRow + wm * 32 + mi * 16 + lg * 4 + r;
                if (row < M) C[(size_t)row * 64 + col] = acc[mi][ni][r] + bv;
            }
        }
    }
}

// ---- aggregation: one wave per node, lane = feature; norm computed in-flight ----
__global__ __launch_bounds__(256) void agg_k(const float* __restrict__ H,
                                             const int* __restrict__ offs,
                                             const int* __restrict__ esrc,
                                             const float* __restrict__ disv,
                                             float* __restrict__ out,
                                             int do_relu) {
    int wv = (blockIdx.x * 256 + threadIdx.x) >> 6;
    int lane = threadIdx.x & 63;
    if (wv >= N_NODES) return;
    float dn = disv[wv];
    float acc = dn * dn * H[(size_t)wv * 64 + lane];   // self loop
    int s = offs[wv], e = offs[wv + 1];
    int i = s;
    for (; i + 8 <= e; i += 8) {
        int src[8]; float hv[8], ws[8];
#pragma unroll
        for (int u = 0; u < 8; u++) src[u] = esrc[i + u];
#pragma unroll
        for (int u = 0; u < 8; u++) {
            hv[u] = H[(size_t)src[u] * 64 + lane];
            ws[u] = disv[src[u]];
        }
#pragma unroll
        for (int u = 0; u < 8; u++) acc = fmaf(dn * ws[u], hv[u], acc);
    }
    int rem = e - i;
    if (rem > 0) {
        int src[8]; float hv[8], ws[8];
#pragma unroll
        for (int u = 0; u < 8; u++) src[u] = esrc[(u < rem) ? (i + u) : i];
#pragma unroll
        for (int u = 0; u < 8; u++) {
            hv[u] = H[(size_t)src[u] * 64 + lane];
            ws[u] = disv[src[u]];
        }
#pragma unroll
        for (int u = 0; u < 8; u++) {
            float nw = (u < rem) ? dn * ws[u] : 0.f;
            acc = fmaf(nw, hv[u], acc);
        }
    }
    if (do_relu) acc = fmaxf(acc, 0.f);
    out[(size_t)wv * 64 + lane] = acc;
}

// ---- fused: conv2 aggregation + output head + log_softmax ----
__global__ __launch_bounds__(256) void agg_out_k(const float* __restrict__ H,
                                                 const int* __restrict__ offs,
                                                 const int* __restrict__ esrc,
                                                 const float* __restrict__ disv,
                                                 const float* __restrict__ Wo,
                                                 const float* __restrict__ bo,
                                                 float* __restrict__ out) {
    __shared__ float Wl[HIDDEN * N_CLASSES];
    __shared__ float bl[N_CLASSES];
    for (int i = threadIdx.x; i < HIDDEN * N_CLASSES; i += 256) Wl[i] = Wo[i];
    if (threadIdx.x < N_CLASSES) bl[threadIdx.x] = bo[threadIdx.x];
    __syncthreads();
    int wv = (blockIdx.x * 256 + threadIdx.x) >> 6;
    int lane = threadIdx.x & 63;
    if (wv >= N_NODES) return;
    float dn = disv[wv];
    float acc = dn * dn * H[(size_t)wv * 64 + lane];
    int s = offs[wv], e = offs[wv + 1];
    int i = s;
    for (; i + 8 <= e; i += 8) {
        int src[8]; float hv[8], ws[8];
#pragma unroll
        for (int u = 0; u < 8; u++) src[u] = esrc[i + u];
#pragma unroll
        for (int u = 0; u < 8; u++) {
            hv[u] = H[(size_t)src[u] * 64 + lane];
            ws[u] = disv[src[u]];
        }
#pragma unroll
        for (int u = 0; u < 8; u++) acc = fmaf(dn * ws[u], hv[u], acc);
    }
    int rem = e - i;
    if (rem > 0) {
        int src[8]; float hv[8], ws[8];
#pragma unroll
        for (int u = 0; u < 8; u++) src[u] = esrc[(u < rem) ? (i + u) : i];
#pragma unroll
        for (int u = 0; u < 8; u++) {
            hv[u] = H[(size_t)src[u] * 64 + lane];
            ws[u] = disv[src[u]];
        }
#pragma unroll
        for (int u = 0; u < 8; u++) {
            float nw = (u < rem) ? dn * ws[u] : 0.f;
            acc = fmaf(nw, hv[u], acc);
        }
    }
    // head: logits = h @ Wo + bo (h[k] = acc of lane k), then log_softmax
    float accL = (lane < N_CLASSES) ? bl[lane] : -1e30f;
#pragma unroll
    for (int k = 0; k < HIDDEN; k++) {
        float xb = __shfl(acc, k);
        if (lane < N_CLASSES) accL = fmaf(xb, Wl[k * N_CLASSES + lane], accL);
    }
    float mx = accL;
#pragma unroll
    for (int d = 32; d; d >>= 1) mx = fmaxf(mx, __shfl_xor(mx, d));
    float ex = (lane < N_CLASSES) ? expf(accL - mx) : 0.f;
    float sm = ex;
#pragma unroll
    for (int d = 32; d; d >>= 1) sm += __shfl_xor(sm, d);
    if (lane < N_CLASSES)
        out[(size_t)wv * N_CLASSES + lane] = accL - mx - logf(sm);
}

extern "C" void kernel_launch(void* const* d_in, const int* in_sizes, int n_in,
                              void* d_out, int out_size, void* d_ws, size_t ws_size,
                              hipStream_t stream) {
    const float* x  = (const float*)d_in[0];
    const float* W1 = (const float*)d_in[1];
    const float* b1 = (const float*)d_in[2];
    const float* W2 = (const float*)d_in[3];
    const float* b2 = (const float*)d_in[4];
    const float* Wo = (const float*)d_in[5];
    const float* bo = (const float*)d_in[6];
    const int* ei   = (const int*)d_in[7];
    const int* erow = ei;
    const int* ecol = ei + N_EDGES;

    char* ws = (char*)d_ws;
    float* h_a    = (float*)(ws + OFF_HA);
    float* h_b    = (float*)(ws + OFF_HB);
    float* disv   = (float*)(ws + OFF_DIS);
    int*   offs   = (int*)(ws + OFF_OFFS);
    int*   histC  = (int*)(ws + OFF_HISTC);
    int*   histR  = (int*)(ws + OFF_HISTR);
    int*   bsum   = (int*)(ws + OFF_BSUM);
    uint*  colS   = (uint*)(ws + OFF_COLS);
    int*   rowS   = (int*)(ws + OFF_ROWS);
    int*   esrc   = (int*)(ws + OFF_ESRC);
    ushort* w1t   = (ushort*)(ws + OFF_W1T);
    ushort* w2t   = (ushort*)(ws + OFF_W2T);
    float* outp   = (float*)d_out;

    // graph build: coarse hist -> scans -> scatter -> fine passes (no global atomics)
    hist_k<<<G_BLOCKS, 256, 0, stream>>>(erow, ecol, histC, histR);
    scan1<<<(SCAN_N + 1023) / 1024, 256, 0, stream>>>(histC, histC, bsum, SCAN_N);
    scan2<<<1, 64, 0, stream>>>(bsum, (SCAN_N + 1023) / 1024);
    scan3<<<(SCAN_N + 255) / 256, 256, 0, stream>>>(histC, bsum, SCAN_N);
    scan1<<<(SCAN_N + 1023) / 1024, 256, 0, stream>>>(histR, histR, bsum, SCAN_N);
    scan2<<<1, 64, 0, stream>>>(bsum, (SCAN_N + 1023) / 1024);
    scan3<<<(SCAN_N + 255) / 256, 256, 0, stream>>>(histR, bsum, SCAN_N);
    scatter_k<<<G_BLOCKS, 256, 0, stream>>>(erow, ecol, histC, histR, colS, rowS);
    fine_row<<<NBINS, 256, 0, stream>>>(rowS, histR, disv);
    fine_col<<<NBINS, 256, 0, stream>>>(colS, histC, offs, esrc);

    // weights -> bf16 transposed
    transpose_w<<<(N_IN * 64 + 255) / 256, 256, 0, stream>>>(W1, w1t, N_IN);
    transpose_w<<<(HIDDEN * 64 + 255) / 256, 256, 0, stream>>>(W2, w2t, HIDDEN);

    // conv1: lin (MFMA bf16) -> aggregate(+relu)
    gemm_mfma<<<(N_NODES + 63) / 64, 256, 0, stream>>>(x, w1t, b1, h_a, N_NODES, N_IN);
    agg_k<<<(N_NODES + 3) / 4, 256, 0, stream>>>(h_a, offs, esrc, disv, h_b, 1);
    // conv2: lin -> fused aggregate + head + log_softmax
    gemm_mfma<<<(N_NODES + 63) / 64, 256, 0, stream>>>(h_b, w2t, b2, h_a, N_NODES, HIDDEN);
    agg_out_k<<<(N_NODES + 3) / 4, 256, 0, stream>>>(h_a, offs, esrc, disv, Wo, bo, outp);
}

// Round 5
// 171.576 us; speedup vs baseline: 2.3665x; 1.1129x over previous
//
#include <hip/hip_runtime.h>
#include <hip/hip_fp16.h>
#include <cstdint>

// Problem constants (from reference)
#define N_NODES   50000
#define N_IN      512
#define HIDDEN    64
#define N_CLASSES 40
#define N_EDGES   800000

// Radix build parameters
#define G_BLOCKS  200                 // blocks in hist/scatter passes
#define EPB       4000                // edges per block (G_BLOCKS*EPB == N_EDGES)
#define NBINS     196                 // ceil(50000/256), bin = node >> 8
#define SCAN_N    (NBINS * G_BLOCKS)  // 39200
#define SCAN_NB   ((SCAN_N + 1023) / 1024)   // 39

// Workspace layout (byte offsets, 16B-aligned)
#define OFF_HA    0u          // 50000*64*2 bf16 = 6,400,000
#define OFF_HB    6400000u    // 6,400,000
#define OFF_DIS   12800000u   // 50000 floats = 200,000
#define OFF_OFFS  13000000u   // 50001 ints = 200,004 -> pad 200,016
#define OFF_HISTC 13200016u   // 39200 ints = 156,800
#define OFF_HISTR 13356816u   // 39200 ints = 156,800
#define OFF_BSUM  13513616u   // 128 ints = 512
#define OFF_COLS  13514128u   // 800000 u32 packed (r | c<<16) = 3,200,000
#define OFF_ROWS  16714128u   // 800000 ints = 3,200,000
#define OFF_EPACK 19914128u   // 800000 u32 (fp16 norm | src) = 3,200,000
#define OFF_W1T   23114128u   // 64*512 bf16 = 65,536
#define OFF_W2T   23179664u   // 64*64 bf16 = 8,192
// total ~23.2 MB

typedef __attribute__((ext_vector_type(8))) short short8_t;
typedef __attribute__((ext_vector_type(4))) float f32x4;

__device__ __forceinline__ ushort f2bf(float f) {
    uint u = __float_as_uint(f);
    uint r = (u + 0x7FFFu + ((u >> 16) & 1u)) >> 16;   // RNE
    return (ushort)r;
}
__device__ __forceinline__ float bf2f(ushort h) {
    return __uint_as_float((uint)h << 16);
}

// ---- stage 1: per-block coarse histograms (LDS only, no global atomics) ----
__global__ __launch_bounds__(256) void hist_k(const int* __restrict__ erow,
                                              const int* __restrict__ ecol,
                                              int* __restrict__ histC,
                                              int* __restrict__ histR) {
    __shared__ int hc[NBINS], hr[NBINS];
    int t = threadIdx.x, b = blockIdx.x;
    if (t < NBINS) { hc[t] = 0; hr[t] = 0; }
    __syncthreads();
    int s = b * EPB;
    for (int i = s + t; i < s + EPB; i += 256) {
        atomicAdd(&hc[ecol[i] >> 8], 1);
        atomicAdd(&hr[erow[i] >> 8], 1);
    }
    __syncthreads();
    if (t < NBINS) {
        histC[t * G_BLOCKS + b] = hc[t];   // [bin][block] layout for bin-major scan
        histR[t * G_BLOCKS + b] = hr[t];
    }
}

// ---- exclusive scan over histC (y=0) and histR (y=1), in-place ----
__global__ __launch_bounds__(256) void scan1(int* __restrict__ histC,
                                             int* __restrict__ histR,
                                             int* __restrict__ bsum, int n) {
    int* a  = blockIdx.y ? histR : histC;
    int* bs = bsum + blockIdx.y * 64;
    int t = threadIdx.x;
    int g = blockIdx.x * 1024 + t * 4;
    int v[4];
#pragma unroll
    for (int i = 0; i < 4; i++) v[i] = (g + i < n) ? a[g + i] : 0;
    int s = v[0] + v[1] + v[2] + v[3];
    int lane = t & 63, wid = t >> 6;
    int x = s;
#pragma unroll
    for (int d = 1; d < 64; d <<= 1) {
        int y = __shfl_up(x, d);
        if (lane >= d) x += y;
    }
    __shared__ int wt[4];
    if (lane == 63) wt[wid] = x;
    __syncthreads();
    int wo = 0;
    for (int w = 0; w < wid; w++) wo += wt[w];
    int run = wo + x - s;
#pragma unroll
    for (int i = 0; i < 4; i++) {
        if (g + i < n) a[g + i] = run;
        run += v[i];
    }
    if (t == 255) bs[blockIdx.x] = wo + x;
}

__global__ void scan2(int* bsum, int nb) {
    int* bs = bsum + blockIdx.x * 64;
    int lane = threadIdx.x;   // 64 threads
    int v = (lane < nb) ? bs[lane] : 0;
    int x = v;
#pragma unroll
    for (int d = 1; d < 64; d <<= 1) {
        int y = __shfl_up(x, d);
        if (lane >= d) x += y;
    }
    if (lane < nb) bs[lane] = x - v;   // exclusive
}

__global__ __launch_bounds__(256) void scan3(int* __restrict__ histC,
                                             int* __restrict__ histR,
                                             const int* __restrict__ bsum, int n) {
    int* a = blockIdx.y ? histR : histC;
    const int* bs = bsum + blockIdx.y * 64;
    int i = blockIdx.x * 256 + threadIdx.x;
    if (i < n) a[i] += bs[i >> 10];
}

// ---- stage 3: radix scatter into bin-sorted order (LDS cursors) ----
__global__ __launch_bounds__(256) void scatter_k(const int* __restrict__ erow,
                                                 const int* __restrict__ ecol,
                                                 const int* __restrict__ scC,
                                                 const int* __restrict__ scR,
                                                 uint* __restrict__ colSorted,
                                                 int* __restrict__ rowSorted) {
    __shared__ int curC[NBINS], curR[NBINS];
    int t = threadIdx.x, b = blockIdx.x;
    if (t < NBINS) {
        curC[t] = scC[t * G_BLOCKS + b];
        curR[t] = scR[t * G_BLOCKS + b];
    }
    __syncthreads();
    int s = b * EPB;
    for (int i = s + t; i < s + EPB; i += 256) {
        int r = erow[i], c = ecol[i];
        int p = atomicAdd(&curC[c >> 8], 1);
        colSorted[p] = (uint)r | ((uint)c << 16);   // both < 50000 < 2^16
        int q = atomicAdd(&curR[r >> 8], 1);
        rowSorted[q] = r;
    }
}

// ---- stage 4a: fine row counts -> disv (deg^-0.5 with self loop) ----
__global__ __launch_bounds__(256) void fine_row(const int* __restrict__ rowSorted,
                                                const int* __restrict__ scR,
                                                float* __restrict__ disv) {
    __shared__ int cnt[256];
    int bin = blockIdx.x, t = threadIdx.x;
    int base = scR[bin * G_BLOCKS];
    int end  = (bin == NBINS - 1) ? N_EDGES : scR[(bin + 1) * G_BLOCKS];
    cnt[t] = 0;
    __syncthreads();
    for (int i = base + t; i < end; i += 256)
        atomicAdd(&cnt[rowSorted[i] & 255], 1);
    __syncthreads();
    int node = bin * 256 + t;
    if (node < N_NODES) disv[node] = rsqrtf((float)(cnt[t] + 1));
}

// ---- stage 4b: fine col pass -> offs (CSR) + epack {fp16 norm | src} ----
__global__ __launch_bounds__(256) void fine_col(const uint* __restrict__ colSorted,
                                                const int* __restrict__ scC,
                                                const float* __restrict__ disv,
                                                int* __restrict__ offs,
                                                uint* __restrict__ epack) {
    __shared__ int cnt[256];
    __shared__ int excl[256];
    __shared__ int wt[4];
    int bin = blockIdx.x, t = threadIdx.x;
    int base = scC[bin * G_BLOCKS];
    int end  = (bin == NBINS - 1) ? N_EDGES : scC[(bin + 1) * G_BLOCKS];
    cnt[t] = 0;
    __syncthreads();
    for (int i = base + t; i < end; i += 256)
        atomicAdd(&cnt[(colSorted[i] >> 16) & 255], 1);
    __syncthreads();
    // exclusive scan of cnt[256]
    int lane = t & 63, w = t >> 6;
    int v = cnt[t];
    int x = v;
#pragma unroll
    for (int d = 1; d < 64; d <<= 1) {
        int y = __shfl_up(x, d);
        if (lane >= d) x += y;
    }
    if (lane == 63) wt[w] = x;
    __syncthreads();
    int wo = 0;
    for (int u = 0; u < w; u++) wo += wt[u];
    excl[t] = wo + x - v;
    cnt[t] = 0;              // reuse as fill cursor
    int node = bin * 256 + t;
    if (node <= N_NODES) offs[node] = base + wo + x - v;  // sentinel at 50000 ok
    __syncthreads();
    for (int i = base + t; i < end; i += 256) {
        uint pv = colSorted[i];
        int cl = (pv >> 16) & 255;
        int src = (int)(pv & 0xFFFFu);
        int p = base + excl[cl] + atomicAdd(&cnt[cl], 1);
        ushort nb_ = __half_as_ushort(__float2half_rn(disv[src]));
        epack[p] = ((uint)nb_ << 16) | (uint)src;
    }
}

// ---- transpose+cast both weight matrices in one launch ----
__global__ __launch_bounds__(256) void transpose_w2(const float* __restrict__ W1,
                                                    const float* __restrict__ W2,
                                                    ushort* __restrict__ w1t,
                                                    ushort* __restrict__ w2t) {
    int i = blockIdx.x * 256 + threadIdx.x;
    if (i < N_IN * 64) {
        int k = i >> 6, n = i & 63;
        w1t[n * N_IN + k] = f2bf(W1[i]);
    } else if (i < N_IN * 64 + HIDDEN * 64) {
        int j = i - N_IN * 64;
        int k = j >> 6, n = j & 63;
        w2t[n * HIDDEN + k] = f2bf(W2[j]);
    }
}

// ---- MFMA GEMM: C[M,64](bf16) = A[M,K] @ WT[64,K](bf16) + bias ----
// ABF16: A is bf16 (ushort rows); else fp32 converted during staging.
template <bool ABF16>
__global__ __launch_bounds__(256) void gemm_mfma(const void* __restrict__ Av,
                                                 const ushort* __restrict__ WT,
                                                 const float* __restrict__ bias,
                                                 ushort* __restrict__ C,
                                                 int M, int K) {
    __shared__ ushort Asb[64][72];   // [m][k], +8 pad
    __shared__ ushort Bsb[64][72];   // [n][k], +8 pad
    int t = threadIdx.x;
    int w = t >> 6, lane = t & 63;
    int wm = w >> 1, wn = w & 1;           // 2x2 wave grid
    int lr = lane & 15, lg = lane >> 4;    // frag row, k-group
    int blockRow = blockIdx.x * 64;

    f32x4 acc[2][2];
#pragma unroll
    for (int i = 0; i < 2; i++)
#pragma unroll
        for (int j = 0; j < 2; j++) acc[i][j] = (f32x4){0.f, 0.f, 0.f, 0.f};

    for (int kk = 0; kk < K; kk += 64) {
#pragma unroll
        for (int u = 0; u < 2; u++) {
            int idx = t + u * 256;
            int m = idx >> 3;
            int k8 = (idx & 7) * 8;
            int row = blockRow + m;
            short8_t s;
            if (ABF16) {
                const ushort* A16 = (const ushort*)Av;
                if (row < M) s = *(const short8_t*)(A16 + (size_t)row * K + kk + k8);
                else s = (short8_t){0,0,0,0,0,0,0,0};
            } else {
                const float* A32 = (const float*)Av;
                float4 a0, a1;
                if (row < M) {
                    const float* p = A32 + (size_t)row * K + kk + k8;
                    a0 = *(const float4*)p;
                    a1 = *(const float4*)(p + 4);
                } else {
                    a0 = make_float4(0.f, 0.f, 0.f, 0.f);
                    a1 = a0;
                }
                s[0] = (short)f2bf(a0.x); s[1] = (short)f2bf(a0.y);
                s[2] = (short)f2bf(a0.z); s[3] = (short)f2bf(a0.w);
                s[4] = (short)f2bf(a1.x); s[5] = (short)f2bf(a1.y);
                s[6] = (short)f2bf(a1.z); s[7] = (short)f2bf(a1.w);
            }
            *(short8_t*)&Asb[m][k8] = s;
        }
#pragma unroll
        for (int u = 0; u < 2; u++) {
            int idx = t + u * 256;
            int n = idx >> 3;
            int k8 = (idx & 7) * 8;
            short8_t vv = *(const short8_t*)(WT + (size_t)n * K + kk + k8);
            *(short8_t*)&Bsb[n][k8] = vv;
        }
        __syncthreads();
#pragma unroll
        for (int ks = 0; ks < 2; ks++) {
            int k0 = ks * 32 + lg * 8;
            short8_t af[2], bf_[2];
#pragma unroll
            for (int mi = 0; mi < 2; mi++)
                af[mi] = *(const short8_t*)&Asb[wm * 32 + mi * 16 + lr][k0];
#pragma unroll
            for (int ni = 0; ni < 2; ni++)
                bf_[ni] = *(const short8_t*)&Bsb[wn * 32 + ni * 16 + lr][k0];
#pragma unroll
            for (int mi = 0; mi < 2; mi++)
#pragma unroll
                for (int ni = 0; ni < 2; ni++)
                    acc[mi][ni] = __builtin_amdgcn_mfma_f32_16x16x32_bf16(
                        af[mi], bf_[ni], acc[mi][ni], 0, 0, 0);
        }
        __syncthreads();
    }
#pragma unroll
    for (int mi = 0; mi < 2; mi++) {
#pragma unroll
        for (int ni = 0; ni < 2; ni++) {
            int col = wn * 32 + ni * 16 + lr;
            float bv = bias[col];
#pragma unroll
            for (int r = 0; r < 4; r++) {
                int row = blockRow + wm * 32 + mi * 16 + lg * 4 + r;
                if (row < M) C[(size_t)row * 64 + col] = f2bf(acc[mi][ni][r] + bv);
            }
        }
    }
}

// ---- aggregation: one wave per node, lane = feature; bf16 H, packed edges ----
__global__ __launch_bounds__(256) void agg_k(const ushort* __restrict__ H,
                                             const int* __restrict__ offs,
                                             const uint* __restrict__ epack,
                                             const float* __restrict__ disv,
                                             ushort* __restrict__ out,
                                             int do_relu) {
    int wv = (blockIdx.x * 256 + threadIdx.x) >> 6;
    int lane = threadIdx.x & 63;
    if (wv >= N_NODES) return;
    float dn = disv[wv];
    float acc = dn * dn * bf2f(H[(size_t)wv * 64 + lane]);   // self loop
    int s = offs[wv], e = offs[wv + 1];
    int i = s;
    for (; i + 8 <= e; i += 8) {
        uint ep[8]; ushort hv[8];
#pragma unroll
        for (int u = 0; u < 8; u++) ep[u] = epack[i + u];
#pragma unroll
        for (int u = 0; u < 8; u++)
            hv[u] = H[(size_t)(ep[u] & 0xFFFFu) * 64 + lane];
#pragma unroll
        for (int u = 0; u < 8; u++) {
            float w = dn * __half2float(__ushort_as_half((ushort)(ep[u] >> 16)));
            acc = fmaf(w, bf2f(hv[u]), acc);
        }
    }
    int rem = e - i;
    if (rem > 0) {
        uint ep[8]; ushort hv[8];
#pragma unroll
        for (int u = 0; u < 8; u++) ep[u] = epack[(u < rem) ? (i + u) : i];
#pragma unroll
        for (int u = 0; u < 8; u++)
            hv[u] = H[(size_t)(ep[u] & 0xFFFFu) * 64 + lane];
#pragma unroll
        for (int u = 0; u < 8; u++) {
            float w = (u < rem)
                ? dn * __half2float(__ushort_as_half((ushort)(ep[u] >> 16))) : 0.f;
            acc = fmaf(w, bf2f(hv[u]), acc);
        }
    }
    if (do_relu) acc = fmaxf(acc, 0.f);
    out[(size_t)wv * 64 + lane] = f2bf(acc);
}

// ---- fused: conv2 aggregation + output head + log_softmax ----
__global__ __launch_bounds__(256) void agg_out_k(const ushort* __restrict__ H,
                                                 const int* __restrict__ offs,
                                                 const uint* __restrict__ epack,
                                                 const float* __restrict__ disv,
                                                 const float* __restrict__ Wo,
                                                 const float* __restrict__ bo,
                                                 float* __restrict__ out) {
    __shared__ float Wl[HIDDEN * N_CLASSES];
    __shared__ float bl[N_CLASSES];
    for (int i = threadIdx.x; i < HIDDEN * N_CLASSES; i += 256) Wl[i] = Wo[i];
    if (threadIdx.x < N_CLASSES) bl[threadIdx.x] = bo[threadIdx.x];
    __syncthreads();
    int wv = (blockIdx.x * 256 + threadIdx.x) >> 6;
    int lane = threadIdx.x & 63;
    if (wv >= N_NODES) return;
    float dn = disv[wv];
    float acc = dn * dn * bf2f(H[(size_t)wv * 64 + lane]);
    int s = offs[wv], e = offs[wv + 1];
    int i = s;
    for (; i + 8 <= e; i += 8) {
        uint ep[8]; ushort hv[8];
#pragma unroll
        for (int u = 0; u < 8; u++) ep[u] = epack[i + u];
#pragma unroll
        for (int u = 0; u < 8; u++)
            hv[u] = H[(size_t)(ep[u] & 0xFFFFu) * 64 + lane];
#pragma unroll
        for (int u = 0; u < 8; u++) {
            float w = dn * __half2float(__ushort_as_half((ushort)(ep[u] >> 16)));
            acc = fmaf(w, bf2f(hv[u]), acc);
        }
    }
    int rem = e - i;
    if (rem > 0) {
        uint ep[8]; ushort hv[8];
#pragma unroll
        for (int u = 0; u < 8; u++) ep[u] = epack[(u < rem) ? (i + u) : i];
#pragma unroll
        for (int u = 0; u < 8; u++)
            hv[u] = H[(size_t)(ep[u] & 0xFFFFu) * 64 + lane];
#pragma unroll
        for (int u = 0; u < 8; u++) {
            float w = (u < rem)
                ? dn * __half2float(__ushort_as_half((ushort)(ep[u] >> 16))) : 0.f;
            acc = fmaf(w, bf2f(hv[u]), acc);
        }
    }
    // head: logits = h @ Wo + bo (h[k] = acc of lane k), then log_softmax
    float accL = (lane < N_CLASSES) ? bl[lane] : -1e30f;
#pragma unroll
    for (int k = 0; k < HIDDEN; k++) {
        float xb = __shfl(acc, k);
        if (lane < N_CLASSES) accL = fmaf(xb, Wl[k * N_CLASSES + lane], accL);
    }
    float mx = accL;
#pragma unroll
    for (int d = 32; d; d >>= 1) mx = fmaxf(mx, __shfl_xor(mx, d));
    float ex = (lane < N_CLASSES) ? expf(accL - mx) : 0.f;
    float sm = ex;
#pragma unroll
    for (int d = 32; d; d >>= 1) sm += __shfl_xor(sm, d);
    if (lane < N_CLASSES)
        out[(size_t)wv * N_CLASSES + lane] = accL - mx - logf(sm);
}

extern "C" void kernel_launch(void* const* d_in, const int* in_sizes, int n_in,
                              void* d_out, int out_size, void* d_ws, size_t ws_size,
                              hipStream_t stream) {
    const float* x  = (const float*)d_in[0];
    const float* W1 = (const float*)d_in[1];
    const float* b1 = (const float*)d_in[2];
    const float* W2 = (const float*)d_in[3];
    const float* b2 = (const float*)d_in[4];
    const float* Wo = (const float*)d_in[5];
    const float* bo = (const float*)d_in[6];
    const int* ei   = (const int*)d_in[7];
    const int* erow = ei;
    const int* ecol = ei + N_EDGES;

    char* ws = (char*)d_ws;
    ushort* h_a   = (ushort*)(ws + OFF_HA);
    ushort* h_b   = (ushort*)(ws + OFF_HB);
    float* disv   = (float*)(ws + OFF_DIS);
    int*   offs   = (int*)(ws + OFF_OFFS);
    int*   histC  = (int*)(ws + OFF_HISTC);
    int*   histR  = (int*)(ws + OFF_HISTR);
    int*   bsum   = (int*)(ws + OFF_BSUM);
    uint*  colS   = (uint*)(ws + OFF_COLS);
    int*   rowS   = (int*)(ws + OFF_ROWS);
    uint*  epack  = (uint*)(ws + OFF_EPACK);
    ushort* w1t   = (ushort*)(ws + OFF_W1T);
    ushort* w2t   = (ushort*)(ws + OFF_W2T);
    float* outp   = (float*)d_out;

    // graph build: coarse hist -> scans (C,R fused via gridDim.y) -> scatter -> fine
    hist_k<<<G_BLOCKS, 256, 0, stream>>>(erow, ecol, histC, histR);
    scan1<<<dim3(SCAN_NB, 2), 256, 0, stream>>>(histC, histR, bsum, SCAN_N);
    scan2<<<2, 64, 0, stream>>>(bsum, SCAN_NB);
    scan3<<<dim3((SCAN_N + 255) / 256, 2), 256, 0, stream>>>(histC, histR, bsum, SCAN_N);
    scatter_k<<<G_BLOCKS, 256, 0, stream>>>(erow, ecol, histC, histR, colS, rowS);
    fine_row<<<NBINS, 256, 0, stream>>>(rowS, histR, disv);
    fine_col<<<NBINS, 256, 0, stream>>>(colS, histC, disv, offs, epack);

    // weights -> bf16 transposed (one launch)
    transpose_w2<<<(N_IN * 64 + HIDDEN * 64 + 255) / 256, 256, 0, stream>>>(W1, W2, w1t, w2t);

    // conv1: lin (MFMA bf16) -> aggregate(+relu)
    gemm_mfma<false><<<(N_NODES + 63) / 64, 256, 0, stream>>>(x, w1t, b1, h_a, N_NODES, N_IN);
    agg_k<<<(N_NODES + 3) / 4, 256, 0, stream>>>(h_a, offs, epack, disv, h_b, 1);
    // conv2: lin -> fused aggregate + head + log_softmax
    gemm_mfma<true><<<(N_NODES + 63) / 64, 256, 0, stream>>>(h_b, w2t, b2, h_a, N_NODES, HIDDEN);
    agg_out_k<<<(N_NODES + 3) / 4, 256, 0, stream>>>(h_a, offs, epack, disv, Wo, bo, outp);
}